// Round 1
// baseline (526.816 us; speedup 1.0000x reference)
//
#include <hip/hip_runtime.h>

#define N_NODES 100000
#define N_EDGES 1250000
#define DIM 64
#define EDGE_DIM 10
#define BN_EPS 1e-5f

#define SCAN_CHUNK 1024
#define NB_SCAN ((N_NODES + SCAN_CHUNK - 1) / SCAN_CHUNK)   // 98

// workspace layout (int units). deg+sums adjacent -> one memset.
#define DEG_OFF    0
#define SUMS_OFF_I (DEG_OFF + N_NODES)        // 256 floats
#define OFFS_OFF   (SUMS_OFF_I + 256)
#define CUR_OFF    (OFFS_OFF + N_NODES)
#define BSUM_OFF   (CUR_OFF + N_NODES)
#define REC_OFF    (BSUM_OFF + 128)           // recs: 2 ints/edge {src, e} (both modes)
#define EH_OFF     (REC_OFF + 2 * N_EDGES)    // eh: 6 ints/edge {5x packed bf16, pad} (fast only)

__device__ __forceinline__ unsigned f2bf(float f) {
    unsigned b = __float_as_uint(f);
    return (b + 0x7FFFu + ((b >> 16) & 1u)) >> 16;   // RTNE
}

// -----------------------------------------------------------------------------
// prep: degree histogram + (fast) pack edge_attr -> bf16 side table eh[e]
// eh writes are COALESCED (indexed by e), unlike the old scattered payload.
// -----------------------------------------------------------------------------
extern "C" __global__ __launch_bounds__(256)
void prep_kernel(const int* __restrict__ ei, const float* __restrict__ ea,
                 int* __restrict__ deg, int* __restrict__ eh, int fast)
{
    int t = blockIdx.x * 256 + threadIdx.x;
    int stride = gridDim.x * 256;
    if (fast) {
        for (int e = t; e < N_EDGES; e += stride) {
            const float* a = ea + (size_t)e * EDGE_DIM;
            int w[5];
            #pragma unroll
            for (int k = 0; k < 5; ++k) {
                float2 p = *(const float2*)&a[2 * k];
                w[k] = (int)(f2bf(p.x) | (f2bf(p.y) << 16));
            }
            int2* r = (int2*)(eh + (size_t)e * 6);
            r[0] = make_int2(w[0], w[1]);
            r[1] = make_int2(w[2], w[3]);
            r[2] = make_int2(w[4], 0);
        }
    }
    for (int e = t; e < N_EDGES; e += stride) {
        unsigned d = (unsigned)ei[N_EDGES + e];
        d = d < N_NODES ? d : (N_NODES - 1);
        atomicAdd(&deg[d], 1);
    }
}

// -----------------------------------------------------------------------------
// scan (3 small kernels)
// -----------------------------------------------------------------------------
extern "C" __global__ __launch_bounds__(256)
void scan_bsum_kernel(const int* __restrict__ deg, int* __restrict__ bsum)
{
    __shared__ int sw[4];
    int tid = threadIdx.x;
    int base = blockIdx.x * SCAN_CHUNK + tid * 4;
    int s = 0;
    #pragma unroll
    for (int j = 0; j < 4; ++j) {
        int idx = base + j;
        if (idx < N_NODES) s += deg[idx];
    }
    #pragma unroll
    for (int m = 1; m < 64; m <<= 1) s += __shfl_xor(s, m, 64);
    if ((tid & 63) == 0) sw[tid >> 6] = s;
    __syncthreads();
    if (tid == 0) bsum[blockIdx.x] = sw[0] + sw[1] + sw[2] + sw[3];
}

extern "C" __global__ __launch_bounds__(128)
void scan_top_kernel(int* __restrict__ bsum)
{
    __shared__ int s[128];
    int tid = threadIdx.x;
    int v = (tid < NB_SCAN) ? bsum[tid] : 0;
    s[tid] = v;
    __syncthreads();
    #pragma unroll
    for (int off = 1; off < 128; off <<= 1) {
        int t = (tid >= off) ? s[tid - off] : 0;
        __syncthreads();
        s[tid] += t;
        __syncthreads();
    }
    if (tid < NB_SCAN) bsum[tid] = s[tid] - v;
}

extern "C" __global__ __launch_bounds__(256)
void scan_final_kernel(const int* __restrict__ deg, const int* __restrict__ bsum,
                       int* __restrict__ offs, int* __restrict__ cur)
{
    __shared__ int s[256];
    int tid = threadIdx.x;
    int base = blockIdx.x * SCAN_CHUNK + tid * 4;
    int d[4];
    #pragma unroll
    for (int j = 0; j < 4; ++j) {
        int idx = base + j;
        d[j] = (idx < N_NODES) ? deg[idx] : 0;
    }
    int tot = d[0] + d[1] + d[2] + d[3];
    s[tid] = tot;
    __syncthreads();
    #pragma unroll
    for (int off = 1; off < 256; off <<= 1) {
        int t = (tid >= off) ? s[tid - off] : 0;
        __syncthreads();
        s[tid] += t;
        __syncthreads();
    }
    int b = bsum[blockIdx.x] + s[tid] - tot;
    #pragma unroll
    for (int j = 0; j < 4; ++j) {
        int idx = base + j;
        if (idx < N_NODES) { offs[idx] = b; cur[idx] = b; }
        b += d[j];
    }
}

// -----------------------------------------------------------------------------
// scatter: ONE 8-byte record per edge {src, e} via a single dwordx2 store.
// No edge_attr traffic here anymore.
// -----------------------------------------------------------------------------
extern "C" __global__ __launch_bounds__(256)
void scatter_kernel(const int* __restrict__ ei, int* __restrict__ cur,
                    int* __restrict__ recs)
{
    int e = blockIdx.x * 256 + threadIdx.x;
    if (e >= N_EDGES) return;
    unsigned d = (unsigned)ei[N_EDGES + e];
    unsigned s = (unsigned)ei[e];
    d = d < N_NODES ? d : (N_NODES - 1);
    s = s < N_NODES ? s : (N_NODES - 1);
    int pos = atomicAdd(&cur[d], 1);
    ((int2*)recs)[pos] = make_int2((int)s, (int)e);
}

// -----------------------------------------------------------------------------
// fused node kernel: record-based aggregation + 2-layer MLP + BN partials.
// 64-node tile, 8 waves, 8 nodes/wave, lane = feature.
// 16-wide edge groups: lane-parallel record load + readlane broadcast;
// 16 x-row gathers in flight; payload via uniform-address (scalar) loads.
// LDS: single time-shared weight buffer (W1 then W2) + sT = 33.8 KB -> 4 blk/CU.
// -----------------------------------------------------------------------------
extern "C" __global__ __launch_bounds__(512, 8)
void node_csr_kernel(const float* __restrict__ x,
                     const float* __restrict__ ea,
                     const int* __restrict__ eh,
                     const float* __restrict__ We,
                     const float* __restrict__ be,
                     const int* __restrict__ offs,
                     const int* __restrict__ cur,
                     const int* __restrict__ recs,
                     const float* __restrict__ W1,
                     const float* __restrict__ b1,
                     const float* __restrict__ W2,
                     const float* __restrict__ b2,
                     float* __restrict__ out,
                     float* __restrict__ sums,
                     int fast)
{
    __shared__ __align__(16) float sW[DIM * DIM];   // 16 KB, W1 then W2
    __shared__ __align__(16) float sT[DIM * 68];    // 17.4 KB

    int tid  = threadIdx.x;
    int lane = tid & 63;
    int wv   = tid >> 6;
    int base = blockIdx.x * 64;

    for (int i = tid; i < DIM * DIM; i += 512) sW[i] = W1[i];

    float wcol[EDGE_DIM];
    #pragma unroll
    for (int k = 0; k < EDGE_DIM; ++k) wcol[k] = We[k * DIM + lane];
    float bias = be[lane];

    // ---- phase A: aggregation ----
    #pragma unroll 1
    for (int t = 0; t < 8; ++t) {
        int nl = wv * 8 + t;
        int v  = base + nl;
        float acc = 0.0f;
        if (v < N_NODES) {
            acc = x[(size_t)v * DIM + lane];
            int stt = __builtin_amdgcn_readfirstlane(offs[v]);
            int end = __builtin_amdgcn_readfirstlane(cur[v]);
            int ng  = (end - stt + 15) >> 4;
            #pragma unroll 1
            for (int g = 0; g < ng; ++g) {
                int i0e = stt + g * 16;
                int pl  = i0e + (lane & 15);
                pl = pl < end ? pl : end - 1;
                int2 rv = ((const int2*)recs)[pl];   // 1 VMEM for 16 records
                int su[16], eu[16];
                #pragma unroll
                for (int u = 0; u < 16; ++u) {
                    su[u] = __builtin_amdgcn_readlane(rv.x, u);
                    eu[u] = __builtin_amdgcn_readlane(rv.y, u);
                }
                float xv[16];
                #pragma unroll
                for (int u = 0; u < 16; ++u)
                    xv[u] = x[(size_t)su[u] * DIM + lane];  // 16 gathers in flight
                #pragma unroll
                for (int u = 0; u < 16; ++u) {
                    float m = bias;
                    if (fast) {
                        const int2* ph = (const int2*)(eh + (size_t)eu[u] * 6);
                        int2 q0 = ph[0], q1 = ph[1], q2 = ph[2];
                        unsigned w0 = (unsigned)q0.x, w1 = (unsigned)q0.y;
                        unsigned w2 = (unsigned)q1.x, w3 = (unsigned)q1.y;
                        unsigned w4 = (unsigned)q2.x;
                        m = fmaf(__uint_as_float(w0 << 16),         wcol[0], m);
                        m = fmaf(__uint_as_float(w0 & 0xFFFF0000u), wcol[1], m);
                        m = fmaf(__uint_as_float(w1 << 16),         wcol[2], m);
                        m = fmaf(__uint_as_float(w1 & 0xFFFF0000u), wcol[3], m);
                        m = fmaf(__uint_as_float(w2 << 16),         wcol[4], m);
                        m = fmaf(__uint_as_float(w2 & 0xFFFF0000u), wcol[5], m);
                        m = fmaf(__uint_as_float(w3 << 16),         wcol[6], m);
                        m = fmaf(__uint_as_float(w3 & 0xFFFF0000u), wcol[7], m);
                        m = fmaf(__uint_as_float(w4 << 16),         wcol[8], m);
                        m = fmaf(__uint_as_float(w4 & 0xFFFF0000u), wcol[9], m);
                    } else {
                        const float* a = ea + (size_t)eu[u] * EDGE_DIM;
                        #pragma unroll
                        for (int k = 0; k < EDGE_DIM; ++k)
                            m = fmaf(a[k], wcol[k], m);
                    }
                    float c = fmaxf(m + xv[u], 0.0f);
                    acc += (i0e + u < end) ? c : 0.0f;
                }
            }
        }
        sT[lane * 68 + nl] = acc;
    }
    __syncthreads();

    // ---- phase B: two GEMMs, 4 nodes x 2 feats per thread ----
    int i0 = (tid & 15) * 4;
    int j0 = (tid >> 4) * 2;

    float acc1[4][2] = {};
    #pragma unroll 8
    for (int k = 0; k < DIM; ++k) {
        float4 av = *(const float4*)&sT[k * 68 + i0];
        float bw0 = sW[k * DIM + j0];
        float bw1 = sW[k * DIM + j0 + 1];
        float a4[4] = {av.x, av.y, av.z, av.w};
        #pragma unroll
        for (int a = 0; a < 4; ++a) {
            acc1[a][0] = fmaf(a4[a], bw0, acc1[a][0]);
            acc1[a][1] = fmaf(a4[a], bw1, acc1[a][1]);
        }
    }
    __syncthreads();

    // refill weight buffer with W2 (all GEMM1 reads of sW are done)
    for (int i = tid; i < DIM * DIM; i += 512) sW[i] = W2[i];

    float b1a[2] = {b1[j0], b1[j0 + 1]};
    float tv[4][2];
    #pragma unroll
    for (int a = 0; a < 4; ++a)
        #pragma unroll
        for (int b = 0; b < 2; ++b)
            tv[a][b] = fmaxf(acc1[a][b] + b1a[b], 0.0f);

    #pragma unroll
    for (int b = 0; b < 2; ++b) {
        float4 w = make_float4(tv[0][b], tv[1][b], tv[2][b], tv[3][b]);
        *(float4*)&sT[(j0 + b) * 68 + i0] = w;
    }
    __syncthreads();

    float acc2[4][2] = {};
    #pragma unroll 8
    for (int k = 0; k < DIM; ++k) {
        float4 av = *(const float4*)&sT[k * 68 + i0];
        float bw0 = sW[k * DIM + j0];
        float bw1 = sW[k * DIM + j0 + 1];
        float a4[4] = {av.x, av.y, av.z, av.w};
        #pragma unroll
        for (int a = 0; a < 4; ++a) {
            acc2[a][0] = fmaf(a4[a], bw0, acc2[a][0]);
            acc2[a][1] = fmaf(a4[a], bw1, acc2[a][1]);
        }
    }

    float b2a[2] = {b2[j0], b2[j0 + 1]};
    float ps[2] = {0.f, 0.f};
    float pq[2] = {0.f, 0.f};
    #pragma unroll
    for (int a = 0; a < 4; ++a) {
        int n = base + i0 + a;
        float r0 = fmaxf(acc2[a][0] + b2a[0], 0.0f);
        float r1 = fmaxf(acc2[a][1] + b2a[1], 0.0f);
        if (n < N_NODES) {
            float2 w = make_float2(r0, r1);
            *(float2*)&out[(size_t)n * DIM + j0] = w;
            ps[0] += r0; ps[1] += r1;
            pq[0] += r0 * r0; pq[1] += r1 * r1;
        }
    }

    #pragma unroll
    for (int m = 1; m < 16; m <<= 1) {
        #pragma unroll
        for (int b = 0; b < 2; ++b) {
            ps[b] += __shfl_xor(ps[b], m, 64);
            pq[b] += __shfl_xor(pq[b], m, 64);
        }
    }
    if ((lane & 15) == 0) {
        #pragma unroll
        for (int b = 0; b < 2; ++b) {
            unsafeAtomicAdd(&sums[j0 + b], ps[b]);
            unsafeAtomicAdd(&sums[64 + j0 + b], pq[b]);
        }
    }
}

// -----------------------------------------------------------------------------
// BN stats + apply
// -----------------------------------------------------------------------------
extern "C" __global__ void bn_stats_kernel(float* __restrict__ sums,
                                           const float* __restrict__ gamma,
                                           const float* __restrict__ beta)
{
    int f = threadIdx.x;
    float inv_n = 1.0f / (float)N_NODES;
    float mean = sums[f] * inv_n;
    float var  = sums[64 + f] * inv_n - mean * mean;
    float sc   = gamma[f] * rsqrtf(var + BN_EPS);
    sums[128 + f] = sc;
    sums[192 + f] = beta[f] - mean * sc;
}

extern "C" __global__ __launch_bounds__(256)
void bn_apply_kernel(float* __restrict__ out, const float* __restrict__ sums)
{
    int j = blockIdx.x * 256 + threadIdx.x;
    int f0 = (j & 15) * 4;
    float4 sc = *(const float4*)&sums[128 + f0];
    float4 sh = *(const float4*)&sums[192 + f0];
    float4 v = ((float4*)out)[j];
    v.x = fmaf(v.x, sc.x, sh.x);
    v.y = fmaf(v.y, sc.y, sh.y);
    v.z = fmaf(v.z, sc.z, sh.z);
    v.w = fmaf(v.w, sc.w, sh.w);
    ((float4*)out)[j] = v;
}

extern "C" void kernel_launch(void* const* d_in, const int* in_sizes, int n_in,
                              void* d_out, int out_size, void* d_ws, size_t ws_size,
                              hipStream_t stream)
{
    const float* x     = (const float*)d_in[0];
    const int*   ei    = (const int*)  d_in[1];
    const float* ea    = (const float*)d_in[2];
    const float* We    = (const float*)d_in[3];
    const float* be    = (const float*)d_in[4];
    const float* W1    = (const float*)d_in[5];
    const float* b1    = (const float*)d_in[6];
    const float* W2    = (const float*)d_in[7];
    const float* b2    = (const float*)d_in[8];
    const float* gamma = (const float*)d_in[9];
    const float* beta  = (const float*)d_in[10];

    float* out  = (float*)d_out;
    int*   wsi  = (int*)d_ws;
    int*   deg  = wsi + DEG_OFF;
    float* sums = (float*)(wsi + SUMS_OFF_I);
    int*   offs = wsi + OFFS_OFF;
    int*   cur  = wsi + CUR_OFF;
    int*   bsum = wsi + BSUM_OFF;
    int*   recs = wsi + REC_OFF;
    int*   eh   = wsi + EH_OFF;

    // fast mode needs recs (8 B/edge) + eh (24 B/edge)
    size_t need_fast = ((size_t)EH_OFF + 6u * N_EDGES) * 4u;
    int fast = (ws_size >= need_fast) ? 1 : 0;

    // zero deg + BN sums (adjacent) in one memset
    hipMemsetAsync(wsi, 0, (size_t)(N_NODES + 256) * sizeof(int), stream);

    prep_kernel<<<2048, 256, 0, stream>>>(ei, ea, deg, eh, fast);
    scan_bsum_kernel<<<NB_SCAN, 256, 0, stream>>>(deg, bsum);
    scan_top_kernel<<<1, 128, 0, stream>>>(bsum);
    scan_final_kernel<<<NB_SCAN, 256, 0, stream>>>(deg, bsum, offs, cur);
    scatter_kernel<<<(N_EDGES + 255) / 256, 256, 0, stream>>>(ei, cur, recs);

    node_csr_kernel<<<(N_NODES + 63) / 64, 512, 0, stream>>>(
        x, ea, eh, We, be, offs, cur, recs, W1, b1, W2, b2, out, sums, fast);

    bn_stats_kernel<<<1, 64, 0, stream>>>(sums, gamma, beta);

    bn_apply_kernel<<<(N_NODES * DIM / 4) / 256, 256, 0, stream>>>(out, sums);
}

// Round 2
// 495.655 us; speedup vs baseline: 1.0629x; 1.0629x over previous
//
#include <hip/hip_runtime.h>

#define N_NODES 100000
#define N_EDGES 1250000
#define DIM 64
#define EDGE_DIM 10
#define BN_EPS 1e-5f

#define SCAN_CHUNK 1024
#define NB_SCAN ((N_NODES + SCAN_CHUNK - 1) / SCAN_CHUNK)   // 98

// workspace layout (int units). deg+sums adjacent -> one memset.
#define DEG_OFF    0
#define SUMS_OFF_I (DEG_OFF + N_NODES)        // 256 floats
#define OFFS_OFF   (SUMS_OFF_I + 256)
#define CUR_OFF    (OFFS_OFF + N_NODES)
#define BSUM_OFF   (CUR_OFF + N_NODES)
#define REC_OFF    (BSUM_OFF + 128)
// fast: records = 6 dwords/edge {src, w0..w4 packed bf16} at CSR slot (24 B)
// slow: records = 2 dwords/edge {src, e}
// xh (bf16 x copy) follows records in both modes.

__device__ __forceinline__ float bf2f(unsigned short h) {
    return __uint_as_float(((unsigned)h) << 16);
}
__device__ __forceinline__ unsigned f2bf(float f) {
    unsigned b = __float_as_uint(f);
    return (b + 0x7FFFu + ((b >> 16) & 1u)) >> 16;   // RTNE
}

// -----------------------------------------------------------------------------
// prep: x -> bf16 copy (vectorized) + degree histogram
// -----------------------------------------------------------------------------
extern "C" __global__ __launch_bounds__(256)
void prep_kernel(const float* __restrict__ x, unsigned short* __restrict__ xh,
                 const int* __restrict__ ei, int* __restrict__ deg)
{
    int t = blockIdx.x * 256 + threadIdx.x;
    int stride = gridDim.x * 256;
    // pack 4 floats -> 4 bf16 (8 B) per iteration
    for (int i = t; i < N_NODES * DIM / 4; i += stride) {
        float4 v = ((const float4*)x)[i];
        uint2 p;
        p.x = f2bf(v.x) | (f2bf(v.y) << 16);
        p.y = f2bf(v.z) | (f2bf(v.w) << 16);
        ((uint2*)xh)[i] = p;
    }
    for (int e = t; e < N_EDGES; e += stride) {
        unsigned d = (unsigned)ei[N_EDGES + e];
        d = d < N_NODES ? d : (N_NODES - 1);
        atomicAdd(&deg[d], 1);
    }
}

// -----------------------------------------------------------------------------
// scan (3 small kernels)
// -----------------------------------------------------------------------------
extern "C" __global__ __launch_bounds__(256)
void scan_bsum_kernel(const int* __restrict__ deg, int* __restrict__ bsum)
{
    __shared__ int sw[4];
    int tid = threadIdx.x;
    int base = blockIdx.x * SCAN_CHUNK + tid * 4;
    int s = 0;
    #pragma unroll
    for (int j = 0; j < 4; ++j) {
        int idx = base + j;
        if (idx < N_NODES) s += deg[idx];
    }
    #pragma unroll
    for (int m = 1; m < 64; m <<= 1) s += __shfl_xor(s, m, 64);
    if ((tid & 63) == 0) sw[tid >> 6] = s;
    __syncthreads();
    if (tid == 0) bsum[blockIdx.x] = sw[0] + sw[1] + sw[2] + sw[3];
}

extern "C" __global__ __launch_bounds__(128)
void scan_top_kernel(int* __restrict__ bsum)
{
    __shared__ int s[128];
    int tid = threadIdx.x;
    int v = (tid < NB_SCAN) ? bsum[tid] : 0;
    s[tid] = v;
    __syncthreads();
    #pragma unroll
    for (int off = 1; off < 128; off <<= 1) {
        int t = (tid >= off) ? s[tid - off] : 0;
        __syncthreads();
        s[tid] += t;
        __syncthreads();
    }
    if (tid < NB_SCAN) bsum[tid] = s[tid] - v;
}

extern "C" __global__ __launch_bounds__(256)
void scan_final_kernel(const int* __restrict__ deg, const int* __restrict__ bsum,
                       int* __restrict__ offs, int* __restrict__ cur)
{
    __shared__ int s[256];
    int tid = threadIdx.x;
    int base = blockIdx.x * SCAN_CHUNK + tid * 4;
    int d[4];
    #pragma unroll
    for (int j = 0; j < 4; ++j) {
        int idx = base + j;
        d[j] = (idx < N_NODES) ? deg[idx] : 0;
    }
    int tot = d[0] + d[1] + d[2] + d[3];
    s[tid] = tot;
    __syncthreads();
    #pragma unroll
    for (int off = 1; off < 256; off <<= 1) {
        int t = (tid >= off) ? s[tid - off] : 0;
        __syncthreads();
        s[tid] += t;
        __syncthreads();
    }
    int b = bsum[blockIdx.x] + s[tid] - tot;
    #pragma unroll
    for (int j = 0; j < 4; ++j) {
        int idx = base + j;
        if (idx < N_NODES) { offs[idx] = b; cur[idx] = b; }
        b += d[j];
    }
}

// -----------------------------------------------------------------------------
// scatter: one record per edge at its CSR slot.
// fast: {src, w0..w4} (24 B, 3x int2 stores); slow: {src, e} (8 B)
// -----------------------------------------------------------------------------
extern "C" __global__ __launch_bounds__(256)
void scatter_kernel(const int* __restrict__ ei, const float* __restrict__ ea,
                    int* __restrict__ cur, int* __restrict__ recs, int fast)
{
    int e = blockIdx.x * 256 + threadIdx.x;
    if (e >= N_EDGES) return;
    unsigned d = (unsigned)ei[N_EDGES + e];
    unsigned s = (unsigned)ei[e];
    d = d < N_NODES ? d : (N_NODES - 1);
    s = s < N_NODES ? s : (N_NODES - 1);
    int pos = atomicAdd(&cur[d], 1);
    if (fast) {
        const float* a = ea + (size_t)e * EDGE_DIM;
        unsigned w[5];
        #pragma unroll
        for (int k = 0; k < 5; ++k) {
            float2 p = *(const float2*)&a[2 * k];
            w[k] = f2bf(p.x) | (f2bf(p.y) << 16);
        }
        int2* r = (int2*)(recs + (size_t)pos * 6);
        r[0] = make_int2((int)s, (int)w[0]);
        r[1] = make_int2((int)w[1], (int)w[2]);
        r[2] = make_int2((int)w[3], (int)w[4]);
    } else {
        ((int2*)recs)[pos] = make_int2((int)s, e);
    }
}

// -----------------------------------------------------------------------------
// fused node kernel: record-based aggregation + 2-layer MLP + BN partials.
// 64-node tile, 8 waves, 8 nodes/wave, lane = feature.
// 16-edge groups: the 16 records (96 contiguous dwords) are loaded by TWO
// full-wave dword loads into 2 VGPRs, distributed via compile-time readlane.
// 16 bf16 x-row gathers in flight per group.
// LDS: time-shared weight buffer (W1 then W2) + sT = 33.8 KB -> 4 blk/CU.
// -----------------------------------------------------------------------------
extern "C" __global__ __launch_bounds__(512, 8)
void node_csr_kernel(const unsigned short* __restrict__ xh,
                     const float* __restrict__ ea,
                     const float* __restrict__ We,
                     const float* __restrict__ be,
                     const int* __restrict__ offs,
                     const int* __restrict__ cur,
                     const int* __restrict__ recs,
                     const float* __restrict__ W1,
                     const float* __restrict__ b1,
                     const float* __restrict__ W2,
                     const float* __restrict__ b2,
                     float* __restrict__ out,
                     float* __restrict__ sums,
                     int fast)
{
    __shared__ __align__(16) float sW[DIM * DIM];   // 16 KB, W1 then W2
    __shared__ __align__(16) float sT[DIM * 68];    // 17.4 KB

    int tid  = threadIdx.x;
    int lane = tid & 63;
    int wv   = tid >> 6;
    int base = blockIdx.x * 64;

    for (int i = tid; i < DIM * DIM; i += 512) sW[i] = W1[i];

    float wcol[EDGE_DIM];
    #pragma unroll
    for (int k = 0; k < EDGE_DIM; ++k) wcol[k] = We[k * DIM + lane];
    float bias = be[lane];

    // ---- phase A: aggregation ----
    #pragma unroll 1
    for (int t = 0; t < 8; ++t) {
        int nl = wv * 8 + t;
        int v  = base + nl;
        float acc = 0.0f;
        if (v < N_NODES) {
            acc = bf2f(xh[(size_t)v * DIM + lane]);
            int stt = __builtin_amdgcn_readfirstlane(offs[v]);
            int end = __builtin_amdgcn_readfirstlane(cur[v]);
            int ng  = (end - stt + 15) >> 4;
            if (fast) {
                #pragma unroll 1
                for (int g = 0; g < ng; ++g) {
                    int i0e  = stt + g * 16;
                    int bD   = i0e * 6;                 // dword index of group
                    // 96 dwords = 16 records; reads past `end` stay inside
                    // recs+xh region (safe), results masked below.
                    int v0 = recs[bD + lane];
                    int v1 = recs[bD + 64 + lane];
                    // extract + clamp srcs (uniform scalars), launch gathers
                    int su[16];
                    #pragma unroll
                    for (int u = 0; u < 16; ++u) {
                        int d = 6 * u;
                        int sv = (d < 64) ? __builtin_amdgcn_readlane(v0, d)
                                          : __builtin_amdgcn_readlane(v1, d - 64);
                        unsigned us = (unsigned)sv;
                        su[u] = (us < N_NODES) ? (int)us : 0;
                    }
                    float xv[16];
                    #pragma unroll
                    for (int u = 0; u < 16; ++u)
                        xv[u] = bf2f(xh[(size_t)su[u] * DIM + lane]);
                    #pragma unroll
                    for (int u = 0; u < 16; ++u) {
                        float m = bias;
                        #pragma unroll
                        for (int k = 0; k < 5; ++k) {
                            int d = 6 * u + 1 + k;
                            unsigned w = (unsigned)((d < 64)
                                ? __builtin_amdgcn_readlane(v0, d)
                                : __builtin_amdgcn_readlane(v1, d - 64));
                            m = fmaf(__uint_as_float(w << 16),         wcol[2 * k],     m);
                            m = fmaf(__uint_as_float(w & 0xFFFF0000u), wcol[2 * k + 1], m);
                        }
                        float c = fmaxf(m + xv[u], 0.0f);
                        acc += (i0e + u < end) ? c : 0.0f;
                    }
                }
            } else {
                #pragma unroll 1
                for (int g = 0; g < ng; ++g) {
                    int i0e = stt + g * 16;
                    int bD  = i0e * 2;                  // 32 dwords = 16 records
                    int v0 = recs[bD + lane];
                    int su[16], eu[16];
                    #pragma unroll
                    for (int u = 0; u < 16; ++u) {
                        int sv = __builtin_amdgcn_readlane(v0, 2 * u);
                        eu[u]  = __builtin_amdgcn_readlane(v0, 2 * u + 1);
                        unsigned us = (unsigned)sv;
                        su[u] = (us < N_NODES) ? (int)us : 0;
                        unsigned ue = (unsigned)eu[u];
                        eu[u] = (ue < N_EDGES) ? (int)ue : 0;
                    }
                    float xv[16];
                    #pragma unroll
                    for (int u = 0; u < 16; ++u)
                        xv[u] = bf2f(xh[(size_t)su[u] * DIM + lane]);
                    #pragma unroll
                    for (int u = 0; u < 16; ++u) {
                        float m = bias;
                        const float* a = ea + (size_t)eu[u] * EDGE_DIM;
                        #pragma unroll
                        for (int k = 0; k < EDGE_DIM; ++k)
                            m = fmaf(a[k], wcol[k], m);
                        float c = fmaxf(m + xv[u], 0.0f);
                        acc += (i0e + u < end) ? c : 0.0f;
                    }
                }
            }
        }
        sT[lane * 68 + nl] = acc;
    }
    __syncthreads();

    // ---- phase B: two GEMMs, 4 nodes x 2 feats per thread ----
    int i0 = (tid & 15) * 4;
    int j0 = (tid >> 4) * 2;

    float acc1[4][2] = {};
    #pragma unroll 8
    for (int k = 0; k < DIM; ++k) {
        float4 av = *(const float4*)&sT[k * 68 + i0];
        float bw0 = sW[k * DIM + j0];
        float bw1 = sW[k * DIM + j0 + 1];
        float a4[4] = {av.x, av.y, av.z, av.w};
        #pragma unroll
        for (int a = 0; a < 4; ++a) {
            acc1[a][0] = fmaf(a4[a], bw0, acc1[a][0]);
            acc1[a][1] = fmaf(a4[a], bw1, acc1[a][1]);
        }
    }
    __syncthreads();

    // refill weight buffer with W2 (all GEMM1 reads of sW are done)
    for (int i = tid; i < DIM * DIM; i += 512) sW[i] = W2[i];

    float b1a[2] = {b1[j0], b1[j0 + 1]};
    float tv[4][2];
    #pragma unroll
    for (int a = 0; a < 4; ++a)
        #pragma unroll
        for (int b = 0; b < 2; ++b)
            tv[a][b] = fmaxf(acc1[a][b] + b1a[b], 0.0f);

    #pragma unroll
    for (int b = 0; b < 2; ++b) {
        float4 w = make_float4(tv[0][b], tv[1][b], tv[2][b], tv[3][b]);
        *(float4*)&sT[(j0 + b) * 68 + i0] = w;
    }
    __syncthreads();

    float acc2[4][2] = {};
    #pragma unroll 8
    for (int k = 0; k < DIM; ++k) {
        float4 av = *(const float4*)&sT[k * 68 + i0];
        float bw0 = sW[k * DIM + j0];
        float bw1 = sW[k * DIM + j0 + 1];
        float a4[4] = {av.x, av.y, av.z, av.w};
        #pragma unroll
        for (int a = 0; a < 4; ++a) {
            acc2[a][0] = fmaf(a4[a], bw0, acc2[a][0]);
            acc2[a][1] = fmaf(a4[a], bw1, acc2[a][1]);
        }
    }

    float b2a[2] = {b2[j0], b2[j0 + 1]};
    float ps[2] = {0.f, 0.f};
    float pq[2] = {0.f, 0.f};
    #pragma unroll
    for (int a = 0; a < 4; ++a) {
        int n = base + i0 + a;
        float r0 = fmaxf(acc2[a][0] + b2a[0], 0.0f);
        float r1 = fmaxf(acc2[a][1] + b2a[1], 0.0f);
        if (n < N_NODES) {
            float2 w = make_float2(r0, r1);
            *(float2*)&out[(size_t)n * DIM + j0] = w;
            ps[0] += r0; ps[1] += r1;
            pq[0] += r0 * r0; pq[1] += r1 * r1;
        }
    }

    #pragma unroll
    for (int m = 1; m < 16; m <<= 1) {
        #pragma unroll
        for (int b = 0; b < 2; ++b) {
            ps[b] += __shfl_xor(ps[b], m, 64);
            pq[b] += __shfl_xor(pq[b], m, 64);
        }
    }
    if ((lane & 15) == 0) {
        #pragma unroll
        for (int b = 0; b < 2; ++b) {
            unsafeAtomicAdd(&sums[j0 + b], ps[b]);
            unsafeAtomicAdd(&sums[64 + j0 + b], pq[b]);
        }
    }
}

// -----------------------------------------------------------------------------
// BN stats + apply
// -----------------------------------------------------------------------------
extern "C" __global__ void bn_stats_kernel(float* __restrict__ sums,
                                           const float* __restrict__ gamma,
                                           const float* __restrict__ beta)
{
    int f = threadIdx.x;
    float inv_n = 1.0f / (float)N_NODES;
    float mean = sums[f] * inv_n;
    float var  = sums[64 + f] * inv_n - mean * mean;
    float sc   = gamma[f] * rsqrtf(var + BN_EPS);
    sums[128 + f] = sc;
    sums[192 + f] = beta[f] - mean * sc;
}

extern "C" __global__ __launch_bounds__(256)
void bn_apply_kernel(float* __restrict__ out, const float* __restrict__ sums)
{
    int j = blockIdx.x * 256 + threadIdx.x;
    int f0 = (j & 15) * 4;
    float4 sc = *(const float4*)&sums[128 + f0];
    float4 sh = *(const float4*)&sums[192 + f0];
    float4 v = ((float4*)out)[j];
    v.x = fmaf(v.x, sc.x, sh.x);
    v.y = fmaf(v.y, sc.y, sh.y);
    v.z = fmaf(v.z, sc.z, sh.z);
    v.w = fmaf(v.w, sc.w, sh.w);
    ((float4*)out)[j] = v;
}

extern "C" void kernel_launch(void* const* d_in, const int* in_sizes, int n_in,
                              void* d_out, int out_size, void* d_ws, size_t ws_size,
                              hipStream_t stream)
{
    const float* x     = (const float*)d_in[0];
    const int*   ei    = (const int*)  d_in[1];
    const float* ea    = (const float*)d_in[2];
    const float* We    = (const float*)d_in[3];
    const float* be    = (const float*)d_in[4];
    const float* W1    = (const float*)d_in[5];
    const float* b1    = (const float*)d_in[6];
    const float* W2    = (const float*)d_in[7];
    const float* b2    = (const float*)d_in[8];
    const float* gamma = (const float*)d_in[9];
    const float* beta  = (const float*)d_in[10];

    float* out  = (float*)d_out;
    int*   wsi  = (int*)d_ws;
    int*   deg  = wsi + DEG_OFF;
    float* sums = (float*)(wsi + SUMS_OFF_I);
    int*   offs = wsi + OFFS_OFF;
    int*   cur  = wsi + CUR_OFF;
    int*   bsum = wsi + BSUM_OFF;
    int*   recs = wsi + REC_OFF;

    // fast mode: 24 B/edge records + xh (same layout/threshold as the verified
    // round-0 configuration, 44.4 MB)
    size_t need_fast = ((size_t)REC_OFF + 6u * N_EDGES + (size_t)N_NODES * DIM / 2) * 4u;
    int fast = (ws_size >= need_fast) ? 1 : 0;
    int rec_ints = fast ? 6 * N_EDGES : 2 * N_EDGES;
    unsigned short* xh = (unsigned short*)(wsi + REC_OFF + rec_ints);

    // zero deg + BN sums (adjacent) in one memset
    hipMemsetAsync(wsi, 0, (size_t)(N_NODES + 256) * sizeof(int), stream);

    prep_kernel<<<2048, 256, 0, stream>>>(x, xh, ei, deg);
    scan_bsum_kernel<<<NB_SCAN, 256, 0, stream>>>(deg, bsum);
    scan_top_kernel<<<1, 128, 0, stream>>>(bsum);
    scan_final_kernel<<<NB_SCAN, 256, 0, stream>>>(deg, bsum, offs, cur);
    scatter_kernel<<<(N_EDGES + 255) / 256, 256, 0, stream>>>(ei, ea, cur, recs, fast);

    node_csr_kernel<<<(N_NODES + 63) / 64, 512, 0, stream>>>(
        xh, ea, We, be, offs, cur, recs, W1, b1, W2, b2, out, sums, fast);

    bn_stats_kernel<<<1, 64, 0, stream>>>(sums, gamma, beta);

    bn_apply_kernel<<<(N_NODES * DIM / 4) / 256, 256, 0, stream>>>(out, sums);
}

// Round 3
// 458.698 us; speedup vs baseline: 1.1485x; 1.0806x over previous
//
#include <hip/hip_runtime.h>

#define N_NODES 100000
#define N_EDGES 1250000
#define DIM 64
#define EDGE_DIM 10
#define BN_EPS 1e-5f

#define SCAN_CHUNK 1024
#define NB_SCAN ((N_NODES + SCAN_CHUNK - 1) / SCAN_CHUNK)   // 98

// workspace layout (int units). deg+sums adjacent -> one memset.
#define DEG_OFF    0
#define SUMS_OFF_I (DEG_OFF + N_NODES)        // 256 floats
#define OFFS_OFF   (SUMS_OFF_I + 256)
#define CUR_OFF    (OFFS_OFF + N_NODES)
#define BSUM_OFF   (CUR_OFF + N_NODES)
#define REC_OFF    (BSUM_OFF + 128)
// fast: records = 6 dwords/edge {src, w0..w4 packed bf16} at CSR slot (24 B)
// slow: records = 2 dwords/edge {src, e}
// xh (bf16 x copy) follows records in both modes.

__device__ __forceinline__ float bf2f(unsigned short h) {
    return __uint_as_float(((unsigned)h) << 16);
}
__device__ __forceinline__ unsigned f2bf(float f) {
    unsigned b = __float_as_uint(f);
    return (b + 0x7FFFu + ((b >> 16) & 1u)) >> 16;   // RTNE
}

// -----------------------------------------------------------------------------
// prep: x -> bf16 copy (vectorized) + degree histogram
// -----------------------------------------------------------------------------
extern "C" __global__ __launch_bounds__(256)
void prep_kernel(const float* __restrict__ x, unsigned short* __restrict__ xh,
                 const int* __restrict__ ei, int* __restrict__ deg)
{
    int t = blockIdx.x * 256 + threadIdx.x;
    int stride = gridDim.x * 256;
    for (int i = t; i < N_NODES * DIM / 4; i += stride) {
        float4 v = ((const float4*)x)[i];
        uint2 p;
        p.x = f2bf(v.x) | (f2bf(v.y) << 16);
        p.y = f2bf(v.z) | (f2bf(v.w) << 16);
        ((uint2*)xh)[i] = p;
    }
    for (int e = t; e < N_EDGES; e += stride) {
        unsigned d = (unsigned)ei[N_EDGES + e];
        d = d < N_NODES ? d : (N_NODES - 1);
        atomicAdd(&deg[d], 1);
    }
}

// -----------------------------------------------------------------------------
// scan (3 small kernels)
// -----------------------------------------------------------------------------
extern "C" __global__ __launch_bounds__(256)
void scan_bsum_kernel(const int* __restrict__ deg, int* __restrict__ bsum)
{
    __shared__ int sw[4];
    int tid = threadIdx.x;
    int base = blockIdx.x * SCAN_CHUNK + tid * 4;
    int s = 0;
    #pragma unroll
    for (int j = 0; j < 4; ++j) {
        int idx = base + j;
        if (idx < N_NODES) s += deg[idx];
    }
    #pragma unroll
    for (int m = 1; m < 64; m <<= 1) s += __shfl_xor(s, m, 64);
    if ((tid & 63) == 0) sw[tid >> 6] = s;
    __syncthreads();
    if (tid == 0) bsum[blockIdx.x] = sw[0] + sw[1] + sw[2] + sw[3];
}

extern "C" __global__ __launch_bounds__(128)
void scan_top_kernel(int* __restrict__ bsum)
{
    __shared__ int s[128];
    int tid = threadIdx.x;
    int v = (tid < NB_SCAN) ? bsum[tid] : 0;
    s[tid] = v;
    __syncthreads();
    #pragma unroll
    for (int off = 1; off < 128; off <<= 1) {
        int t = (tid >= off) ? s[tid - off] : 0;
        __syncthreads();
        s[tid] += t;
        __syncthreads();
    }
    if (tid < NB_SCAN) bsum[tid] = s[tid] - v;
}

extern "C" __global__ __launch_bounds__(256)
void scan_final_kernel(const int* __restrict__ deg, const int* __restrict__ bsum,
                       int* __restrict__ offs, int* __restrict__ cur)
{
    __shared__ int s[256];
    int tid = threadIdx.x;
    int base = blockIdx.x * SCAN_CHUNK + tid * 4;
    int d[4];
    #pragma unroll
    for (int j = 0; j < 4; ++j) {
        int idx = base + j;
        d[j] = (idx < N_NODES) ? deg[idx] : 0;
    }
    int tot = d[0] + d[1] + d[2] + d[3];
    s[tid] = tot;
    __syncthreads();
    #pragma unroll
    for (int off = 1; off < 256; off <<= 1) {
        int t = (tid >= off) ? s[tid - off] : 0;
        __syncthreads();
        s[tid] += t;
        __syncthreads();
    }
    int b = bsum[blockIdx.x] + s[tid] - tot;
    #pragma unroll
    for (int j = 0; j < 4; ++j) {
        int idx = base + j;
        if (idx < N_NODES) { offs[idx] = b; cur[idx] = b; }
        b += d[j];
    }
}

// -----------------------------------------------------------------------------
// scatter: one record per edge at its CSR slot.
// fast: {src, w0..w4} (24 B, 3x int2 stores); slow: {src, e} (8 B)
// -----------------------------------------------------------------------------
extern "C" __global__ __launch_bounds__(256)
void scatter_kernel(const int* __restrict__ ei, const float* __restrict__ ea,
                    int* __restrict__ cur, int* __restrict__ recs, int fast)
{
    int e = blockIdx.x * 256 + threadIdx.x;
    if (e >= N_EDGES) return;
    unsigned d = (unsigned)ei[N_EDGES + e];
    unsigned s = (unsigned)ei[e];
    d = d < N_NODES ? d : (N_NODES - 1);
    s = s < N_NODES ? s : (N_NODES - 1);
    int pos = atomicAdd(&cur[d], 1);
    if (fast) {
        const float* a = ea + (size_t)e * EDGE_DIM;
        unsigned w[5];
        #pragma unroll
        for (int k = 0; k < 5; ++k) {
            float2 p = *(const float2*)&a[2 * k];
            w[k] = f2bf(p.x) | (f2bf(p.y) << 16);
        }
        int2* r = (int2*)(recs + (size_t)pos * 6);
        r[0] = make_int2((int)s, (int)w[0]);
        r[1] = make_int2((int)w[1], (int)w[2]);
        r[2] = make_int2((int)w[3], (int)w[4]);
    } else {
        ((int2*)recs)[pos] = make_int2((int)s, e);
    }
}

// -----------------------------------------------------------------------------
// fused node kernel: aggregation + 2-layer MLP + BN partials.
// Phase A: HALF-WAVE edge mapping. lane = (feature-pair fl=lane&31, edge-parity
// half=lane>>5). Each lane handles 2 features (packed bf16 dword) of its half's
// edge. 16-slot groups = 8 INDEPENDENT pairs -> 8 src loads, 8 row-gathers
// (dword/lane), 40 same-line attr broadcasts all in flight. No readlanes.
// LDS: time-shared sW (W1 then W2) + sT + offs/cur cache = 34.3 KB.
// -----------------------------------------------------------------------------
extern "C" __global__ __launch_bounds__(512)
void node_csr_kernel(const unsigned short* __restrict__ xh,
                     const float* __restrict__ ea,
                     const float* __restrict__ We,
                     const float* __restrict__ be,
                     const int* __restrict__ offs,
                     const int* __restrict__ cur,
                     const int* __restrict__ recs,
                     const float* __restrict__ W1,
                     const float* __restrict__ b1,
                     const float* __restrict__ W2,
                     const float* __restrict__ b2,
                     float* __restrict__ out,
                     float* __restrict__ sums,
                     int fast)
{
    __shared__ __align__(16) float sW[DIM * DIM];   // 16 KB, W1 then W2
    __shared__ __align__(16) float sT[DIM * 68];    // 17.4 KB
    __shared__ int sOffs[64];
    __shared__ int sCur[64];

    int tid  = threadIdx.x;
    int lane = tid & 63;
    int wv   = tid >> 6;
    int base = blockIdx.x * 64;

    int fl   = lane & 31;     // feature pair index: features 2fl, 2fl+1
    int half = lane >> 5;     // edge parity within a slot pair

    for (int i = tid; i < DIM * DIM; i += 512) sW[i] = W1[i];
    if (tid < 64) {
        int v = base + tid;
        v = v < N_NODES ? v : (N_NODES - 1);
        sOffs[tid] = offs[v];
    } else if (tid < 128) {
        int v = base + tid - 64;
        v = v < N_NODES ? v : (N_NODES - 1);
        sCur[tid - 64] = cur[v];
    }

    // per-lane We columns for my 2 features
    float2 wc[EDGE_DIM];
    #pragma unroll
    for (int k = 0; k < EDGE_DIM; ++k)
        wc[k] = *(const float2*)&We[k * DIM + 2 * fl];
    float2 bias2 = *(const float2*)&be[2 * fl];

    const unsigned* xq = (const unsigned*)xh;   // packed bf16 pairs

    __syncthreads();   // sOffs/sCur ready

    // ---- phase A: aggregation ----
    #pragma unroll 1
    for (int t = 0; t < 8; ++t) {
        int nl = wv * 8 + t;
        int v  = base + nl;
        float acc0 = 0.0f, acc1 = 0.0f;
        float o0 = 0.0f, o1 = 0.0f;
        if (v < N_NODES) {
            int stt = __builtin_amdgcn_readfirstlane(sOffs[nl]);
            int end = __builtin_amdgcn_readfirstlane(sCur[nl]);
            int ng  = (end - stt + 15) >> 4;
            if (fast) {
                #pragma unroll 1
                for (int g = 0; g < ng; ++g) {
                    int i0e = stt + g * 16;
                    int voff[8];
                    bool msk[8];
                    #pragma unroll
                    for (int p = 0; p < 8; ++p) {
                        int sl  = i0e + 2 * p + half;
                        msk[p]  = sl < end;
                        int csl = msk[p] ? sl : (end - 1);
                        voff[p] = csl * 6;
                    }
                    int sp[8];
                    #pragma unroll
                    for (int p = 0; p < 8; ++p)
                        sp[p] = recs[voff[p]];            // 8 src loads in flight
                    unsigned xw[8];
                    #pragma unroll
                    for (int p = 0; p < 8; ++p) {
                        unsigned us = (unsigned)sp[p];
                        us = us < N_NODES ? us : 0u;
                        xw[p] = xq[us * 32u + (unsigned)fl];  // 8 gathers in flight
                    }
                    unsigned wa[8][5];
                    #pragma unroll
                    for (int p = 0; p < 8; ++p)
                        #pragma unroll
                        for (int j = 0; j < 5; ++j)
                            wa[p][j] = (unsigned)recs[voff[p] + 1 + j]; // L1 broadcasts
                    #pragma unroll
                    for (int p = 0; p < 8; ++p) {
                        float m0 = bias2.x, m1 = bias2.y;
                        #pragma unroll
                        for (int j = 0; j < 5; ++j) {
                            float alo = __uint_as_float(wa[p][j] << 16);
                            float ahi = __uint_as_float(wa[p][j] & 0xFFFF0000u);
                            m0 = fmaf(alo, wc[2 * j].x,     m0);
                            m1 = fmaf(alo, wc[2 * j].y,     m1);
                            m0 = fmaf(ahi, wc[2 * j + 1].x, m0);
                            m1 = fmaf(ahi, wc[2 * j + 1].y, m1);
                        }
                        float xlo = __uint_as_float(xw[p] << 16);
                        float xhi = __uint_as_float(xw[p] & 0xFFFF0000u);
                        float c0 = fmaxf(m0 + xlo, 0.0f);
                        float c1 = fmaxf(m1 + xhi, 0.0f);
                        acc0 += msk[p] ? c0 : 0.0f;
                        acc1 += msk[p] ? c1 : 0.0f;
                    }
                }
            } else {
                #pragma unroll 1
                for (int g = 0; g < ng; ++g) {
                    int i0e = stt + g * 16;
                    int voff[8];
                    bool msk[8];
                    #pragma unroll
                    for (int p = 0; p < 8; ++p) {
                        int sl  = i0e + 2 * p + half;
                        msk[p]  = sl < end;
                        int csl = msk[p] ? sl : (end - 1);
                        voff[p] = csl * 2;
                    }
                    int sp[8], ep[8];
                    #pragma unroll
                    for (int p = 0; p < 8; ++p) {
                        sp[p] = recs[voff[p]];
                        ep[p] = recs[voff[p] + 1];
                    }
                    unsigned xw[8];
                    #pragma unroll
                    for (int p = 0; p < 8; ++p) {
                        unsigned us = (unsigned)sp[p];
                        us = us < N_NODES ? us : 0u;
                        xw[p] = xq[us * 32u + (unsigned)fl];
                    }
                    #pragma unroll
                    for (int p = 0; p < 8; ++p) {
                        unsigned ue = (unsigned)ep[p];
                        ue = ue < N_EDGES ? ue : 0u;
                        const float* a = ea + (size_t)ue * EDGE_DIM;
                        float m0 = bias2.x, m1 = bias2.y;
                        #pragma unroll
                        for (int k = 0; k < EDGE_DIM; ++k) {
                            float av = a[k];
                            m0 = fmaf(av, (&wc[k].x)[0], m0);
                            m1 = fmaf(av, (&wc[k].x)[1], m1);
                        }
                        float xlo = __uint_as_float(xw[p] << 16);
                        float xhi = __uint_as_float(xw[p] & 0xFFFF0000u);
                        float c0 = fmaxf(m0 + xlo, 0.0f);
                        float c1 = fmaxf(m1 + xhi, 0.0f);
                        acc0 += msk[p] ? c0 : 0.0f;
                        acc1 += msk[p] ? c1 : 0.0f;
                    }
                }
            }
            // combine halves (even+odd slots), add own x row
            o0 = acc0 + __shfl_xor(acc0, 32, 64);
            o1 = acc1 + __shfl_xor(acc1, 32, 64);
            unsigned xw = xq[(unsigned)v * 32u + (unsigned)fl];
            o0 += __uint_as_float(xw << 16);
            o1 += __uint_as_float(xw & 0xFFFF0000u);
        }
        if (half == 0) {
            sT[(2 * fl)     * 68 + nl] = o0;
            sT[(2 * fl + 1) * 68 + nl] = o1;
        }
    }
    __syncthreads();

    // ---- phase B: two GEMMs, 4 nodes x 2 feats per thread ----
    int i0 = (tid & 15) * 4;
    int j0 = (tid >> 4) * 2;

    float acc1g[4][2] = {};
    #pragma unroll 8
    for (int k = 0; k < DIM; ++k) {
        float4 av = *(const float4*)&sT[k * 68 + i0];
        float bw0 = sW[k * DIM + j0];
        float bw1 = sW[k * DIM + j0 + 1];
        float a4[4] = {av.x, av.y, av.z, av.w};
        #pragma unroll
        for (int a = 0; a < 4; ++a) {
            acc1g[a][0] = fmaf(a4[a], bw0, acc1g[a][0]);
            acc1g[a][1] = fmaf(a4[a], bw1, acc1g[a][1]);
        }
    }
    __syncthreads();

    // refill weight buffer with W2 (all GEMM1 reads of sW are done)
    for (int i = tid; i < DIM * DIM; i += 512) sW[i] = W2[i];

    float b1a[2] = {b1[j0], b1[j0 + 1]};
    float tv[4][2];
    #pragma unroll
    for (int a = 0; a < 4; ++a)
        #pragma unroll
        for (int b = 0; b < 2; ++b)
            tv[a][b] = fmaxf(acc1g[a][b] + b1a[b], 0.0f);

    #pragma unroll
    for (int b = 0; b < 2; ++b) {
        float4 w = make_float4(tv[0][b], tv[1][b], tv[2][b], tv[3][b]);
        *(float4*)&sT[(j0 + b) * 68 + i0] = w;
    }
    __syncthreads();

    float acc2[4][2] = {};
    #pragma unroll 8
    for (int k = 0; k < DIM; ++k) {
        float4 av = *(const float4*)&sT[k * 68 + i0];
        float bw0 = sW[k * DIM + j0];
        float bw1 = sW[k * DIM + j0 + 1];
        float a4[4] = {av.x, av.y, av.z, av.w};
        #pragma unroll
        for (int a = 0; a < 4; ++a) {
            acc2[a][0] = fmaf(a4[a], bw0, acc2[a][0]);
            acc2[a][1] = fmaf(a4[a], bw1, acc2[a][1]);
        }
    }

    float b2a[2] = {b2[j0], b2[j0 + 1]};
    float ps[2] = {0.f, 0.f};
    float pq[2] = {0.f, 0.f};
    #pragma unroll
    for (int a = 0; a < 4; ++a) {
        int n = base + i0 + a;
        float r0 = fmaxf(acc2[a][0] + b2a[0], 0.0f);
        float r1 = fmaxf(acc2[a][1] + b2a[1], 0.0f);
        if (n < N_NODES) {
            float2 w = make_float2(r0, r1);
            *(float2*)&out[(size_t)n * DIM + j0] = w;
            ps[0] += r0; ps[1] += r1;
            pq[0] += r0 * r0; pq[1] += r1 * r1;
        }
    }

    #pragma unroll
    for (int m = 1; m < 16; m <<= 1) {
        #pragma unroll
        for (int b = 0; b < 2; ++b) {
            ps[b] += __shfl_xor(ps[b], m, 64);
            pq[b] += __shfl_xor(pq[b], m, 64);
        }
    }
    if ((lane & 15) == 0) {
        #pragma unroll
        for (int b = 0; b < 2; ++b) {
            unsafeAtomicAdd(&sums[j0 + b], ps[b]);
            unsafeAtomicAdd(&sums[64 + j0 + b], pq[b]);
        }
    }
}

// -----------------------------------------------------------------------------
// BN stats + apply
// -----------------------------------------------------------------------------
extern "C" __global__ void bn_stats_kernel(float* __restrict__ sums,
                                           const float* __restrict__ gamma,
                                           const float* __restrict__ beta)
{
    int f = threadIdx.x;
    float inv_n = 1.0f / (float)N_NODES;
    float mean = sums[f] * inv_n;
    float var  = sums[64 + f] * inv_n - mean * mean;
    float sc   = gamma[f] * rsqrtf(var + BN_EPS);
    sums[128 + f] = sc;
    sums[192 + f] = beta[f] - mean * sc;
}

extern "C" __global__ __launch_bounds__(256)
void bn_apply_kernel(float* __restrict__ out, const float* __restrict__ sums)
{
    int j = blockIdx.x * 256 + threadIdx.x;
    int f0 = (j & 15) * 4;
    float4 sc = *(const float4*)&sums[128 + f0];
    float4 sh = *(const float4*)&sums[192 + f0];
    float4 v = ((float4*)out)[j];
    v.x = fmaf(v.x, sc.x, sh.x);
    v.y = fmaf(v.y, sc.y, sh.y);
    v.z = fmaf(v.z, sc.z, sh.z);
    v.w = fmaf(v.w, sc.w, sh.w);
    ((float4*)out)[j] = v;
}

extern "C" void kernel_launch(void* const* d_in, const int* in_sizes, int n_in,
                              void* d_out, int out_size, void* d_ws, size_t ws_size,
                              hipStream_t stream)
{
    const float* x     = (const float*)d_in[0];
    const int*   ei    = (const int*)  d_in[1];
    const float* ea    = (const float*)d_in[2];
    const float* We    = (const float*)d_in[3];
    const float* be    = (const float*)d_in[4];
    const float* W1    = (const float*)d_in[5];
    const float* b1    = (const float*)d_in[6];
    const float* W2    = (const float*)d_in[7];
    const float* b2    = (const float*)d_in[8];
    const float* gamma = (const float*)d_in[9];
    const float* beta  = (const float*)d_in[10];

    float* out  = (float*)d_out;
    int*   wsi  = (int*)d_ws;
    int*   deg  = wsi + DEG_OFF;
    float* sums = (float*)(wsi + SUMS_OFF_I);
    int*   offs = wsi + OFFS_OFF;
    int*   cur  = wsi + CUR_OFF;
    int*   bsum = wsi + BSUM_OFF;
    int*   recs = wsi + REC_OFF;

    // fast mode: 24 B/edge records + xh (same verified layout/threshold)
    size_t need_fast = ((size_t)REC_OFF + 6u * N_EDGES + (size_t)N_NODES * DIM / 2) * 4u;
    int fast = (ws_size >= need_fast) ? 1 : 0;
    int rec_ints = fast ? 6 * N_EDGES : 2 * N_EDGES;
    unsigned short* xh = (unsigned short*)(wsi + REC_OFF + rec_ints);

    // zero deg + BN sums (adjacent) in one memset
    hipMemsetAsync(wsi, 0, (size_t)(N_NODES + 256) * sizeof(int), stream);

    prep_kernel<<<2048, 256, 0, stream>>>(x, xh, ei, deg);
    scan_bsum_kernel<<<NB_SCAN, 256, 0, stream>>>(deg, bsum);
    scan_top_kernel<<<1, 128, 0, stream>>>(bsum);
    scan_final_kernel<<<NB_SCAN, 256, 0, stream>>>(deg, bsum, offs, cur);
    scatter_kernel<<<(N_EDGES + 255) / 256, 256, 0, stream>>>(ei, ea, cur, recs, fast);

    node_csr_kernel<<<(N_NODES + 63) / 64, 512, 0, stream>>>(
        xh, ea, We, be, offs, cur, recs, W1, b1, W2, b2, out, sums, fast);

    bn_stats_kernel<<<1, 64, 0, stream>>>(sums, gamma, beta);

    bn_apply_kernel<<<(N_NODES * DIM / 4) / 256, 256, 0, stream>>>(out, sums);
}

// Round 4
// 449.188 us; speedup vs baseline: 1.1728x; 1.0212x over previous
//
#include <hip/hip_runtime.h>

#define N_NODES 100000
#define N_EDGES 1250000
#define DIM 64
#define EDGE_DIM 10
#define BN_EPS 1e-5f

#define SCAN_CHUNK 1024
#define NB_SCAN ((N_NODES + SCAN_CHUNK - 1) / SCAN_CHUNK)   // 98

// workspace layout (int units). deg+sums adjacent -> one memset.
#define DEG_OFF    0
#define SUMS_OFF_I (DEG_OFF + N_NODES)        // 256 floats
#define OFFS_OFF   (SUMS_OFF_I + 256)
#define CUR_OFF    (OFFS_OFF + N_NODES)
#define BSUM_OFF   (CUR_OFF + N_NODES)
#define REC_OFF    (BSUM_OFF + 128)
// fast: records = 6 dwords/edge {src, w0..w4 packed bf16} at CSR slot (24 B)
// slow: records = 2 dwords/edge {src, e}
// xh (bf16 x copy) follows records in both modes.

__device__ __forceinline__ unsigned f2bf(float f) {
    unsigned b = __float_as_uint(f);
    return (b + 0x7FFFu + ((b >> 16) & 1u)) >> 16;   // RTNE
}

// -----------------------------------------------------------------------------
// prep: x -> bf16 copy (vectorized) + degree histogram
// -----------------------------------------------------------------------------
extern "C" __global__ __launch_bounds__(256)
void prep_kernel(const float* __restrict__ x, unsigned short* __restrict__ xh,
                 const int* __restrict__ ei, int* __restrict__ deg)
{
    int t = blockIdx.x * 256 + threadIdx.x;
    int stride = gridDim.x * 256;
    for (int i = t; i < N_NODES * DIM / 4; i += stride) {
        float4 v = ((const float4*)x)[i];
        uint2 p;
        p.x = f2bf(v.x) | (f2bf(v.y) << 16);
        p.y = f2bf(v.z) | (f2bf(v.w) << 16);
        ((uint2*)xh)[i] = p;
    }
    for (int e = t; e < N_EDGES; e += stride) {
        unsigned d = (unsigned)ei[N_EDGES + e];
        d = d < N_NODES ? d : (N_NODES - 1);
        atomicAdd(&deg[d], 1);
    }
}

// -----------------------------------------------------------------------------
// scan (3 small kernels)
// -----------------------------------------------------------------------------
extern "C" __global__ __launch_bounds__(256)
void scan_bsum_kernel(const int* __restrict__ deg, int* __restrict__ bsum)
{
    __shared__ int sw[4];
    int tid = threadIdx.x;
    int base = blockIdx.x * SCAN_CHUNK + tid * 4;
    int s = 0;
    #pragma unroll
    for (int j = 0; j < 4; ++j) {
        int idx = base + j;
        if (idx < N_NODES) s += deg[idx];
    }
    #pragma unroll
    for (int m = 1; m < 64; m <<= 1) s += __shfl_xor(s, m, 64);
    if ((tid & 63) == 0) sw[tid >> 6] = s;
    __syncthreads();
    if (tid == 0) bsum[blockIdx.x] = sw[0] + sw[1] + sw[2] + sw[3];
}

extern "C" __global__ __launch_bounds__(128)
void scan_top_kernel(int* __restrict__ bsum)
{
    __shared__ int s[128];
    int tid = threadIdx.x;
    int v = (tid < NB_SCAN) ? bsum[tid] : 0;
    s[tid] = v;
    __syncthreads();
    #pragma unroll
    for (int off = 1; off < 128; off <<= 1) {
        int t = (tid >= off) ? s[tid - off] : 0;
        __syncthreads();
        s[tid] += t;
        __syncthreads();
    }
    if (tid < NB_SCAN) bsum[tid] = s[tid] - v;
}

extern "C" __global__ __launch_bounds__(256)
void scan_final_kernel(const int* __restrict__ deg, const int* __restrict__ bsum,
                       int* __restrict__ offs, int* __restrict__ cur)
{
    __shared__ int s[256];
    int tid = threadIdx.x;
    int base = blockIdx.x * SCAN_CHUNK + tid * 4;
    int d[4];
    #pragma unroll
    for (int j = 0; j < 4; ++j) {
        int idx = base + j;
        d[j] = (idx < N_NODES) ? deg[idx] : 0;
    }
    int tot = d[0] + d[1] + d[2] + d[3];
    s[tid] = tot;
    __syncthreads();
    #pragma unroll
    for (int off = 1; off < 256; off <<= 1) {
        int t = (tid >= off) ? s[tid - off] : 0;
        __syncthreads();
        s[tid] += t;
        __syncthreads();
    }
    int b = bsum[blockIdx.x] + s[tid] - tot;
    #pragma unroll
    for (int j = 0; j < 4; ++j) {
        int idx = base + j;
        if (idx < N_NODES) { offs[idx] = b; cur[idx] = b; }
        b += d[j];
    }
}

// -----------------------------------------------------------------------------
// scatter: one record per edge at its CSR slot.
// fast: {src, w0..w4} (24 B, 3x int2 stores); slow: {src, e} (8 B)
// -----------------------------------------------------------------------------
extern "C" __global__ __launch_bounds__(256)
void scatter_kernel(const int* __restrict__ ei, const float* __restrict__ ea,
                    int* __restrict__ cur, int* __restrict__ recs, int fast)
{
    int e = blockIdx.x * 256 + threadIdx.x;
    if (e >= N_EDGES) return;
    unsigned d = (unsigned)ei[N_EDGES + e];
    unsigned s = (unsigned)ei[e];
    d = d < N_NODES ? d : (N_NODES - 1);
    s = s < N_NODES ? s : (N_NODES - 1);
    int pos = atomicAdd(&cur[d], 1);
    if (fast) {
        const float* a = ea + (size_t)e * EDGE_DIM;
        unsigned w[5];
        #pragma unroll
        for (int k = 0; k < 5; ++k) {
            float2 p = *(const float2*)&a[2 * k];
            w[k] = f2bf(p.x) | (f2bf(p.y) << 16);
        }
        int2* r = (int2*)(recs + (size_t)pos * 6);
        r[0] = make_int2((int)s, (int)w[0]);
        r[1] = make_int2((int)w[1], (int)w[2]);
        r[2] = make_int2((int)w[3], (int)w[4]);
    } else {
        ((int2*)recs)[pos] = make_int2((int)s, e);
    }
}

// -----------------------------------------------------------------------------
// fused node kernel: aggregation + 2-layer MLP + BN partials.
// Phase A: QUARTER-wave mapping. q=lane>>4 picks slot phase, fq=lane&15 picks
// 4 features. 16-slot group = 4 slots/lane; per group only 16 wave-wide VMEM
// instructions, each carrying 4 distinct addresses. Cross-item prefetch of the
// {src,w0} dwords keeps the next item's srcs resident before its gathers.
// -----------------------------------------------------------------------------

// per-slot message compute: 5 attr dwords (10 bf16) x 4 features + x add + relu
#define SLOT_ACC(W0, Bv, Cv, Xv, MK)                                            \
    {                                                                           \
        float m0 = bias4.x, m1 = bias4.y, m2 = bias4.z, m3 = bias4.w;           \
        unsigned wd_; float a_;                                                 \
        wd_ = (unsigned)(W0);                                                   \
        a_ = __uint_as_float(wd_ << 16);                                        \
        m0 = fmaf(a_, wc[0].x, m0); m1 = fmaf(a_, wc[0].y, m1);                 \
        m2 = fmaf(a_, wc[0].z, m2); m3 = fmaf(a_, wc[0].w, m3);                 \
        a_ = __uint_as_float(wd_ & 0xFFFF0000u);                                \
        m0 = fmaf(a_, wc[1].x, m0); m1 = fmaf(a_, wc[1].y, m1);                 \
        m2 = fmaf(a_, wc[1].z, m2); m3 = fmaf(a_, wc[1].w, m3);                 \
        wd_ = (unsigned)(Bv).x;                                                 \
        a_ = __uint_as_float(wd_ << 16);                                        \
        m0 = fmaf(a_, wc[2].x, m0); m1 = fmaf(a_, wc[2].y, m1);                 \
        m2 = fmaf(a_, wc[2].z, m2); m3 = fmaf(a_, wc[2].w, m3);                 \
        a_ = __uint_as_float(wd_ & 0xFFFF0000u);                                \
        m0 = fmaf(a_, wc[3].x, m0); m1 = fmaf(a_, wc[3].y, m1);                 \
        m2 = fmaf(a_, wc[3].z, m2); m3 = fmaf(a_, wc[3].w, m3);                 \
        wd_ = (unsigned)(Bv).y;                                                 \
        a_ = __uint_as_float(wd_ << 16);                                        \
        m0 = fmaf(a_, wc[4].x, m0); m1 = fmaf(a_, wc[4].y, m1);                 \
        m2 = fmaf(a_, wc[4].z, m2); m3 = fmaf(a_, wc[4].w, m3);                 \
        a_ = __uint_as_float(wd_ & 0xFFFF0000u);                                \
        m0 = fmaf(a_, wc[5].x, m0); m1 = fmaf(a_, wc[5].y, m1);                 \
        m2 = fmaf(a_, wc[5].z, m2); m3 = fmaf(a_, wc[5].w, m3);                 \
        wd_ = (unsigned)(Cv).x;                                                 \
        a_ = __uint_as_float(wd_ << 16);                                        \
        m0 = fmaf(a_, wc[6].x, m0); m1 = fmaf(a_, wc[6].y, m1);                 \
        m2 = fmaf(a_, wc[6].z, m2); m3 = fmaf(a_, wc[6].w, m3);                 \
        a_ = __uint_as_float(wd_ & 0xFFFF0000u);                                \
        m0 = fmaf(a_, wc[7].x, m0); m1 = fmaf(a_, wc[7].y, m1);                 \
        m2 = fmaf(a_, wc[7].z, m2); m3 = fmaf(a_, wc[7].w, m3);                 \
        wd_ = (unsigned)(Cv).y;                                                 \
        a_ = __uint_as_float(wd_ << 16);                                        \
        m0 = fmaf(a_, wc[8].x, m0); m1 = fmaf(a_, wc[8].y, m1);                 \
        m2 = fmaf(a_, wc[8].z, m2); m3 = fmaf(a_, wc[8].w, m3);                 \
        a_ = __uint_as_float(wd_ & 0xFFFF0000u);                                \
        m0 = fmaf(a_, wc[9].x, m0); m1 = fmaf(a_, wc[9].y, m1);                 \
        m2 = fmaf(a_, wc[9].z, m2); m3 = fmaf(a_, wc[9].w, m3);                 \
        float x0_ = __uint_as_float(((unsigned)(Xv).x) << 16);                  \
        float x1_ = __uint_as_float(((unsigned)(Xv).x) & 0xFFFF0000u);          \
        float x2_ = __uint_as_float(((unsigned)(Xv).y) << 16);                  \
        float x3_ = __uint_as_float(((unsigned)(Xv).y) & 0xFFFF0000u);          \
        float c0_ = fmaxf(m0 + x0_, 0.0f);                                      \
        float c1_ = fmaxf(m1 + x1_, 0.0f);                                      \
        float c2_ = fmaxf(m2 + x2_, 0.0f);                                      \
        float c3_ = fmaxf(m3 + x3_, 0.0f);                                      \
        ax += (MK) ? c0_ : 0.0f; ay += (MK) ? c1_ : 0.0f;                       \
        az += (MK) ? c2_ : 0.0f; aw += (MK) ? c3_ : 0.0f;                       \
    }

extern "C" __global__ __launch_bounds__(512)
void node_csr_kernel(const unsigned short* __restrict__ xh,
                     const float* __restrict__ ea,
                     const float* __restrict__ We,
                     const float* __restrict__ be,
                     const int* __restrict__ offs,
                     const int* __restrict__ cur,
                     const int* __restrict__ recs,
                     const float* __restrict__ W1,
                     const float* __restrict__ b1,
                     const float* __restrict__ W2,
                     const float* __restrict__ b2,
                     float* __restrict__ out,
                     float* __restrict__ sums,
                     int fast)
{
    __shared__ __align__(16) float sW[DIM * DIM];   // 16 KB, W1 then W2
    __shared__ __align__(16) float sT[DIM * 68];    // 17.4 KB
    __shared__ int sOffs[64];
    __shared__ int sCur[64];

    int tid  = threadIdx.x;
    int lane = tid & 63;
    int wv   = tid >> 6;
    int base = blockIdx.x * 64;

    int fq = lane & 15;       // feature quad: features 4fq .. 4fq+3
    int q  = lane >> 4;       // slot phase within 16-slot group

    for (int i = tid; i < DIM * DIM; i += 512) sW[i] = W1[i];
    if (tid < 64) {
        int v = base + tid;
        v = v < N_NODES ? v : (N_NODES - 1);
        sOffs[tid] = offs[v];
    } else if (tid < 128) {
        int v = base + tid - 64;
        v = v < N_NODES ? v : (N_NODES - 1);
        sCur[tid - 64] = cur[v];
    }

    // per-lane We columns for my 4 features
    float4 wc[EDGE_DIM];
    #pragma unroll
    for (int k = 0; k < EDGE_DIM; ++k)
        wc[k] = *(const float4*)&We[k * DIM + 4 * fq];
    float4 bias4 = *(const float4*)&be[4 * fq];

    const uint2* xq2 = (const uint2*)xh;   // row = 16 uint2 (32 dwords)
    const int2*  rc2 = (const int2*)recs;  // fast: record p = int2 idx 3p..3p+2

    __syncthreads();   // sOffs/sCur ready

    // ---- phase A: aggregation ----
    if (fast) {
        int2 A0, A1, A2, A3;     // prefetched {src, w0} of the upcoming item
        bool haveA = false;
        #pragma unroll 1
        for (int t = 0; t < 8; ++t) {
            int nl = wv * 8 + t;
            int v  = base + nl;
            float ax = 0.f, ay = 0.f, az = 0.f, aw = 0.f;
            // self-x row: issue early, consumed at finalize
            unsigned vc = (unsigned)(v < N_NODES ? v : (N_NODES - 1));
            uint2 sx = xq2[vc * 16u + (unsigned)fq];
            if (v < N_NODES) {
                int stt = __builtin_amdgcn_readfirstlane(sOffs[nl]);
                int end = __builtin_amdgcn_readfirstlane(sCur[nl]);
                int ng  = (end - stt + 15) >> 4;
                #pragma unroll 1
                for (int g = 0; g < ng; ++g) {
                    int i0e = stt + g * 16;
                    int e1  = end - 1;
                    int s0 = i0e + q, s1 = s0 + 4, s2 = s0 + 8, s3 = s0 + 12;
                    int c0 = 3 * min(s0, e1), c1 = 3 * min(s1, e1);
                    int c2 = 3 * min(s2, e1), c3 = 3 * min(s3, e1);
                    if (!haveA) {              // cold start (rare)
                        A0 = rc2[c0]; A1 = rc2[c1]; A2 = rc2[c2]; A3 = rc2[c3];
                    }
                    // rest of current records: latency hides under gathers
                    int2 B0 = rc2[c0 + 1], C0 = rc2[c0 + 2];
                    int2 B1 = rc2[c1 + 1], C1 = rc2[c1 + 2];
                    int2 B2 = rc2[c2 + 1], C2 = rc2[c2 + 2];
                    int2 B3 = rc2[c3 + 1], C3 = rc2[c3 + 2];
                    // gathers from prefetched srcs
                    unsigned u0 = (unsigned)A0.x; u0 = u0 < N_NODES ? u0 : 0u;
                    unsigned u1 = (unsigned)A1.x; u1 = u1 < N_NODES ? u1 : 0u;
                    unsigned u2 = (unsigned)A2.x; u2 = u2 < N_NODES ? u2 : 0u;
                    unsigned u3 = (unsigned)A3.x; u3 = u3 < N_NODES ? u3 : 0u;
                    uint2 X0 = xq2[u0 * 16u + (unsigned)fq];
                    uint2 X1 = xq2[u1 * 16u + (unsigned)fq];
                    uint2 X2 = xq2[u2 * 16u + (unsigned)fq];
                    uint2 X3 = xq2[u3 * 16u + (unsigned)fq];
                    // save w0 before A is clobbered by prefetch
                    unsigned w00 = (unsigned)A0.y, w01 = (unsigned)A1.y;
                    unsigned w02 = (unsigned)A2.y, w03 = (unsigned)A3.y;
                    // prefetch next item's A-pairs
                    haveA = false;
                    {
                        int tn = t, gn = g + 1, sttn = stt, endn = end;
                        bool ok = (gn < ng);
                        if (!ok) {
                            tn = t + 1; gn = 0;
                            if (tn < 8) {
                                int nln = wv * 8 + tn;
                                int vn  = base + nln;
                                if (vn < N_NODES) {
                                    sttn = __builtin_amdgcn_readfirstlane(sOffs[nln]);
                                    endn = __builtin_amdgcn_readfirstlane(sCur[nln]);
                                    ok = endn > sttn;
                                }
                            }
                        }
                        if (ok) {
                            int i0n = sttn + gn * 16;
                            int en1 = endn - 1;
                            int n0 = 3 * min(i0n + q,      en1);
                            int n1 = 3 * min(i0n + q + 4,  en1);
                            int n2 = 3 * min(i0n + q + 8,  en1);
                            int n3 = 3 * min(i0n + q + 12, en1);
                            A0 = rc2[n0]; A1 = rc2[n1]; A2 = rc2[n2]; A3 = rc2[n3];
                            haveA = true;
                        }
                    }
                    // compute all 4 slots
                    SLOT_ACC(w00, B0, C0, X0, s0 < end);
                    SLOT_ACC(w01, B1, C1, X1, s1 < end);
                    SLOT_ACC(w02, B2, C2, X2, s2 < end);
                    SLOT_ACC(w03, B3, C3, X3, s3 < end);
                }
            }
            // reduce across 4 quarters
            ax += __shfl_xor(ax, 16, 64); ax += __shfl_xor(ax, 32, 64);
            ay += __shfl_xor(ay, 16, 64); ay += __shfl_xor(ay, 32, 64);
            az += __shfl_xor(az, 16, 64); az += __shfl_xor(az, 32, 64);
            aw += __shfl_xor(aw, 16, 64); aw += __shfl_xor(aw, 32, 64);
            if (v < N_NODES) {
                ax += __uint_as_float(sx.x << 16);
                ay += __uint_as_float(sx.x & 0xFFFF0000u);
                az += __uint_as_float(sx.y << 16);
                aw += __uint_as_float(sx.y & 0xFFFF0000u);
            }
            if (q == 0) {
                sT[(4 * fq + 0) * 68 + nl] = ax;
                sT[(4 * fq + 1) * 68 + nl] = ay;
                sT[(4 * fq + 2) * 68 + nl] = az;
                sT[(4 * fq + 3) * 68 + nl] = aw;
            }
        }
    } else {
        // slow fallback: {src, e} records, fp32 edge attrs
        #pragma unroll 1
        for (int t = 0; t < 8; ++t) {
            int nl = wv * 8 + t;
            int v  = base + nl;
            float ax = 0.f, ay = 0.f, az = 0.f, aw = 0.f;
            unsigned vc = (unsigned)(v < N_NODES ? v : (N_NODES - 1));
            uint2 sx = xq2[vc * 16u + (unsigned)fq];
            if (v < N_NODES) {
                int stt = __builtin_amdgcn_readfirstlane(sOffs[nl]);
                int end = __builtin_amdgcn_readfirstlane(sCur[nl]);
                int ng  = (end - stt + 15) >> 4;
                #pragma unroll 1
                for (int g = 0; g < ng; ++g) {
                    int i0e = stt + g * 16;
                    int e1  = end - 1;
                    int s0 = i0e + q, s1 = s0 + 4, s2 = s0 + 8, s3 = s0 + 12;
                    int2 A0 = ((const int2*)recs)[min(s0, e1)];
                    int2 A1 = ((const int2*)recs)[min(s1, e1)];
                    int2 A2 = ((const int2*)recs)[min(s2, e1)];
                    int2 A3 = ((const int2*)recs)[min(s3, e1)];
                    unsigned u0 = (unsigned)A0.x; u0 = u0 < N_NODES ? u0 : 0u;
                    unsigned u1 = (unsigned)A1.x; u1 = u1 < N_NODES ? u1 : 0u;
                    unsigned u2 = (unsigned)A2.x; u2 = u2 < N_NODES ? u2 : 0u;
                    unsigned u3 = (unsigned)A3.x; u3 = u3 < N_NODES ? u3 : 0u;
                    uint2 X0 = xq2[u0 * 16u + (unsigned)fq];
                    uint2 X1 = xq2[u1 * 16u + (unsigned)fq];
                    uint2 X2 = xq2[u2 * 16u + (unsigned)fq];
                    uint2 X3 = xq2[u3 * 16u + (unsigned)fq];
                    #pragma unroll
                    for (int p = 0; p < 4; ++p) {
                        int sl = p == 0 ? s0 : p == 1 ? s1 : p == 2 ? s2 : s3;
                        unsigned ue = (unsigned)(p == 0 ? A0.y : p == 1 ? A1.y :
                                                 p == 2 ? A2.y : A3.y);
                        ue = ue < N_EDGES ? ue : 0u;
                        uint2 Xv = p == 0 ? X0 : p == 1 ? X1 : p == 2 ? X2 : X3;
                        const float* a = ea + (size_t)ue * EDGE_DIM;
                        float m0 = bias4.x, m1 = bias4.y, m2 = bias4.z, m3 = bias4.w;
                        #pragma unroll
                        for (int k = 0; k < EDGE_DIM; ++k) {
                            float av = a[k];
                            m0 = fmaf(av, wc[k].x, m0);
                            m1 = fmaf(av, wc[k].y, m1);
                            m2 = fmaf(av, wc[k].z, m2);
                            m3 = fmaf(av, wc[k].w, m3);
                        }
                        float x0_ = __uint_as_float(Xv.x << 16);
                        float x1_ = __uint_as_float(Xv.x & 0xFFFF0000u);
                        float x2_ = __uint_as_float(Xv.y << 16);
                        float x3_ = __uint_as_float(Xv.y & 0xFFFF0000u);
                        bool mk = sl < end;
                        ax += mk ? fmaxf(m0 + x0_, 0.f) : 0.f;
                        ay += mk ? fmaxf(m1 + x1_, 0.f) : 0.f;
                        az += mk ? fmaxf(m2 + x2_, 0.f) : 0.f;
                        aw += mk ? fmaxf(m3 + x3_, 0.f) : 0.f;
                    }
                }
            }
            ax += __shfl_xor(ax, 16, 64); ax += __shfl_xor(ax, 32, 64);
            ay += __shfl_xor(ay, 16, 64); ay += __shfl_xor(ay, 32, 64);
            az += __shfl_xor(az, 16, 64); az += __shfl_xor(az, 32, 64);
            aw += __shfl_xor(aw, 16, 64); aw += __shfl_xor(aw, 32, 64);
            if (v < N_NODES) {
                ax += __uint_as_float(sx.x << 16);
                ay += __uint_as_float(sx.x & 0xFFFF0000u);
                az += __uint_as_float(sx.y << 16);
                aw += __uint_as_float(sx.y & 0xFFFF0000u);
            }
            if (q == 0) {
                sT[(4 * fq + 0) * 68 + nl] = ax;
                sT[(4 * fq + 1) * 68 + nl] = ay;
                sT[(4 * fq + 2) * 68 + nl] = az;
                sT[(4 * fq + 3) * 68 + nl] = aw;
            }
        }
    }
    __syncthreads();

    // ---- phase B: two GEMMs, 4 nodes x 2 feats per thread ----
    int i0 = (tid & 15) * 4;
    int j0 = (tid >> 4) * 2;

    float acc1g[4][2] = {};
    #pragma unroll 8
    for (int k = 0; k < DIM; ++k) {
        float4 av = *(const float4*)&sT[k * 68 + i0];
        float bw0 = sW[k * DIM + j0];
        float bw1 = sW[k * DIM + j0 + 1];
        float a4[4] = {av.x, av.y, av.z, av.w};
        #pragma unroll
        for (int a = 0; a < 4; ++a) {
            acc1g[a][0] = fmaf(a4[a], bw0, acc1g[a][0]);
            acc1g[a][1] = fmaf(a4[a], bw1, acc1g[a][1]);
        }
    }
    __syncthreads();

    // refill weight buffer with W2 (all GEMM1 reads of sW are done)
    for (int i = tid; i < DIM * DIM; i += 512) sW[i] = W2[i];

    float b1a[2] = {b1[j0], b1[j0 + 1]};
    float tv[4][2];
    #pragma unroll
    for (int a = 0; a < 4; ++a)
        #pragma unroll
        for (int b = 0; b < 2; ++b)
            tv[a][b] = fmaxf(acc1g[a][b] + b1a[b], 0.0f);

    #pragma unroll
    for (int b = 0; b < 2; ++b) {
        float4 w = make_float4(tv[0][b], tv[1][b], tv[2][b], tv[3][b]);
        *(float4*)&sT[(j0 + b) * 68 + i0] = w;
    }
    __syncthreads();

    float acc2[4][2] = {};
    #pragma unroll 8
    for (int k = 0; k < DIM; ++k) {
        float4 av = *(const float4*)&sT[k * 68 + i0];
        float bw0 = sW[k * DIM + j0];
        float bw1 = sW[k * DIM + j0 + 1];
        float a4[4] = {av.x, av.y, av.z, av.w};
        #pragma unroll
        for (int a = 0; a < 4; ++a) {
            acc2[a][0] = fmaf(a4[a], bw0, acc2[a][0]);
            acc2[a][1] = fmaf(a4[a], bw1, acc2[a][1]);
        }
    }

    float b2a[2] = {b2[j0], b2[j0 + 1]};
    float ps[2] = {0.f, 0.f};
    float pq[2] = {0.f, 0.f};
    #pragma unroll
    for (int a = 0; a < 4; ++a) {
        int n = base + i0 + a;
        float r0 = fmaxf(acc2[a][0] + b2a[0], 0.0f);
        float r1 = fmaxf(acc2[a][1] + b2a[1], 0.0f);
        if (n < N_NODES) {
            float2 w = make_float2(r0, r1);
            *(float2*)&out[(size_t)n * DIM + j0] = w;
            ps[0] += r0; ps[1] += r1;
            pq[0] += r0 * r0; pq[1] += r1 * r1;
        }
    }

    #pragma unroll
    for (int m = 1; m < 16; m <<= 1) {
        #pragma unroll
        for (int b = 0; b < 2; ++b) {
            ps[b] += __shfl_xor(ps[b], m, 64);
            pq[b] += __shfl_xor(pq[b], m, 64);
        }
    }
    if ((lane & 15) == 0) {
        #pragma unroll
        for (int b = 0; b < 2; ++b) {
            unsafeAtomicAdd(&sums[j0 + b], ps[b]);
            unsafeAtomicAdd(&sums[64 + j0 + b], pq[b]);
        }
    }
}

// -----------------------------------------------------------------------------
// BN apply with inline stats (bn_stats kernel folded in)
// -----------------------------------------------------------------------------
extern "C" __global__ __launch_bounds__(256)
void bn_apply_kernel(float* __restrict__ out, const float* __restrict__ sums,
                     const float* __restrict__ gamma, const float* __restrict__ beta)
{
    int j = blockIdx.x * 256 + threadIdx.x;
    int f0 = (j & 15) * 4;
    float4 s1 = *(const float4*)&sums[f0];
    float4 s2 = *(const float4*)&sums[64 + f0];
    float4 gm = *(const float4*)&gamma[f0];
    float4 bt = *(const float4*)&beta[f0];
    const float inv_n = 1.0f / (float)N_NODES;
    float4 sc, sh;
    {
        float m = s1.x * inv_n; float vv = fmaf(-m, m, s2.x * inv_n);
        sc.x = gm.x * rsqrtf(vv + BN_EPS); sh.x = fmaf(-m, sc.x, bt.x);
    }
    {
        float m = s1.y * inv_n; float vv = fmaf(-m, m, s2.y * inv_n);
        sc.y = gm.y * rsqrtf(vv + BN_EPS); sh.y = fmaf(-m, sc.y, bt.y);
    }
    {
        float m = s1.z * inv_n; float vv = fmaf(-m, m, s2.z * inv_n);
        sc.z = gm.z * rsqrtf(vv + BN_EPS); sh.z = fmaf(-m, sc.z, bt.z);
    }
    {
        float m = s1.w * inv_n; float vv = fmaf(-m, m, s2.w * inv_n);
        sc.w = gm.w * rsqrtf(vv + BN_EPS); sh.w = fmaf(-m, sc.w, bt.w);
    }
    float4 v = ((float4*)out)[j];
    v.x = fmaf(v.x, sc.x, sh.x);
    v.y = fmaf(v.y, sc.y, sh.y);
    v.z = fmaf(v.z, sc.z, sh.z);
    v.w = fmaf(v.w, sc.w, sh.w);
    ((float4*)out)[j] = v;
}

extern "C" void kernel_launch(void* const* d_in, const int* in_sizes, int n_in,
                              void* d_out, int out_size, void* d_ws, size_t ws_size,
                              hipStream_t stream)
{
    const float* x     = (const float*)d_in[0];
    const int*   ei    = (const int*)  d_in[1];
    const float* ea    = (const float*)d_in[2];
    const float* We    = (const float*)d_in[3];
    const float* be    = (const float*)d_in[4];
    const float* W1    = (const float*)d_in[5];
    const float* b1    = (const float*)d_in[6];
    const float* W2    = (const float*)d_in[7];
    const float* b2    = (const float*)d_in[8];
    const float* gamma = (const float*)d_in[9];
    const float* beta  = (const float*)d_in[10];

    float* out  = (float*)d_out;
    int*   wsi  = (int*)d_ws;
    int*   deg  = wsi + DEG_OFF;
    float* sums = (float*)(wsi + SUMS_OFF_I);
    int*   offs = wsi + OFFS_OFF;
    int*   cur  = wsi + CUR_OFF;
    int*   bsum = wsi + BSUM_OFF;
    int*   recs = wsi + REC_OFF;

    // fast mode: 24 B/edge records + xh (same verified layout/threshold)
    size_t need_fast = ((size_t)REC_OFF + 6u * N_EDGES + (size_t)N_NODES * DIM / 2) * 4u;
    int fast = (ws_size >= need_fast) ? 1 : 0;
    int rec_ints = fast ? 6 * N_EDGES : 2 * N_EDGES;
    unsigned short* xh = (unsigned short*)(wsi + REC_OFF + rec_ints);

    // zero deg + BN sums (adjacent) in one memset
    hipMemsetAsync(wsi, 0, (size_t)(N_NODES + 256) * sizeof(int), stream);

    prep_kernel<<<2048, 256, 0, stream>>>(x, xh, ei, deg);
    scan_bsum_kernel<<<NB_SCAN, 256, 0, stream>>>(deg, bsum);
    scan_top_kernel<<<1, 128, 0, stream>>>(bsum);
    scan_final_kernel<<<NB_SCAN, 256, 0, stream>>>(deg, bsum, offs, cur);
    scatter_kernel<<<(N_EDGES + 255) / 256, 256, 0, stream>>>(ei, ea, cur, recs, fast);

    node_csr_kernel<<<(N_NODES + 63) / 64, 512, 0, stream>>>(
        xh, ea, We, be, offs, cur, recs, W1, b1, W2, b2, out, sums, fast);

    bn_apply_kernel<<<(N_NODES * DIM / 4) / 256, 256, 0, stream>>>(out, sums, gamma, beta);
}